// Round 16
// baseline (537.392 us; speedup 1.0000x reference)
//
#include <hip/hip_runtime.h>

#define INV_N (1.0f / 4096.0f)

typedef __fp16 half2_t __attribute__((ext_vector_type(2)));
typedef float  f32x2   __attribute__((ext_vector_type(2)));

__device__ __forceinline__ unsigned pack_h2(f32x2 v) {
    half2_t h = __builtin_amdgcn_cvt_pkrtz(v.x, v.y);   // v_cvt_pkrtz_f16_f32
    return __builtin_bit_cast(unsigned, h);
}
__device__ __forceinline__ f32x2 unpack_h2(unsigned u) {
    half2_t h = __builtin_bit_cast(half2_t, u);
    return (f32x2){(float)h.x, (float)h.y};
}

// Packed butterfly: (re,im) as one f32x2. t = cv*b + sv*swap(b) with
// cv=(cs,cs), sv=(-s,s) maps to v_pk_mul_f32/v_pk_fma_f32 on CDNA
// (dual-fp32 packed ops) — 3-4 packed instrs vs 8 scalar. R15 showed VALU
// is now co-dominant (VALUBusy 46%); this halves the butterfly op count.
__device__ __forceinline__ void bf2(f32x2& a, f32x2& b, f32x2 cv, f32x2 sv) {
    f32x2 bs = {b.y, b.x};
    f32x2 t  = cv * b + sv * bs;
    b = a - t;
    a = a + t;
}

// Twiddle: angle = -2pi*(k/4096)*wk radians => rev = -(k/4096)*wk revolutions.
__device__ __forceinline__ void tw2(int k, float wk, f32x2* cv, f32x2* sv) {
    float rev = (float)k * (-INV_N) * wk;
    rev = __builtin_amdgcn_fractf(rev);          // [0,1), handles negatives
    float s  = __builtin_amdgcn_sinf(rev);       // sin(2*pi*rev)
    float cs = __builtin_amdgcn_cosf(rev);       // cos(2*pi*rev)
    *cv = (f32x2){cs, cs};
    *sv = (f32x2){-s, s};
}

#define CV_ID ((f32x2){1.f, 1.f})
#define SV_ID ((f32x2){0.f, 0.f})

// Raw barrier with LDS-only drain. __syncthreads() would emit
// "s_waitcnt vmcnt(0) lgkmcnt(0)" and drain the global-load queue at every
// exchange barrier; lgkmcnt(0)-only lets in-flight global loads ride through
// (R10: the only overlap lever that measurably helped).
#define BAR() do { asm volatile("s_waitcnt lgkmcnt(0)" ::: "memory"); \
                   __builtin_amdgcn_s_barrier(); } while (0)

// Two-round 16 KB ownership exchange: consecutive-16 rows -> stride-4 rows.
// Parity predicate (pb + (m>>2) + (m&3)) & 1: what a thread flushes in a
// round is exactly what it refills in that round (no extra live VGPRs).
__device__ __forceinline__ void exchange(f32x2* tile, f32x2 (&v)[16],
                                         int pb, int c) {
#pragma unroll
    for (int par = 0; par < 2; ++par) {
#pragma unroll
        for (int m = 0; m < 16; ++m) {
            if (((pb + (m >> 2) + (m & 3)) & 1) == par) {
                int srow = (pb << 3) + (((m >> 2) << 1) | ((m & 3) >> 1));
                tile[srow * 64 + c] = v[m];
            }
        }
        BAR();
#pragma unroll
        for (int m = 0; m < 16; ++m) {
            if (((pb + (m >> 2) + (m & 3)) & 1) == par) {
                int srow = ((m >> 2) << 3) + ((m & 3) << 1) + (pb >> 1);
                v[m] = tile[srow * 64 + c];
            }
        }
        if (par == 0) BAR();
    }
}

// Kernel A: stages step=2..64 (R15 structure; packed-f32 butterflies).
// HALF_OUT=1 stores the intermediate as packed fp16 (4 B/elem, R15 win).
template <int HALF_OUT>
__global__ __launch_bounds__(256) void fft_lo(const float* __restrict__ x,
                                              const float* __restrict__ w,
                                              void* __restrict__ dstv,
                                              unsigned dst_lim) {   // element units
    __shared__ __align__(16) f32x2 tile[32 * 64];   // 16 KB, exchange only
    const int t   = threadIdx.x;
    const int c   = t & 63;
    const int pb  = t >> 6;
    const int c0  = (blockIdx.x & 63) << 6;
    const int r0  = (blockIdx.x >> 6) << 6;
    const int src_r0 = r0 ^ 2048;      // initial permutation: new[i] = old[i^2048]
    const unsigned col = (unsigned)(c0 + c);

    f32x2 v[16];
    // ---- 1) data rows 0..7 ----
#pragma unroll
    for (int m = 0; m < 8; ++m) {
        unsigned gi = (unsigned)(src_r0 + 16 * pb + m) * 4096u + col;
        v[m] = (f32x2){__builtin_nontemporal_load(&x[gi]), 0.f};
    }
    // ---- 2) w for half-stage twiddles s1[2],s1[4],s1[6] ----
    float wpe[3];
#pragma unroll
    for (int i = 0; i < 3; ++i)
        wpe[i] = w[(unsigned)(512 * (i + 1)) * 4096u + col];
    // ---- 3) data rows 8..15 ----
#pragma unroll
    for (int m = 8; m < 16; ++m) {
        unsigned gi = (unsigned)(src_r0 + 16 * pb + m) * 4096u + col;
        v[m] = (f32x2){__builtin_nontemporal_load(&x[gi]), 0.f};
    }
    // ---- 4) w for cross-stage twiddles s1[1,3,5,7] ----
    float wpo[4];
#pragma unroll
    for (int i = 0; i < 4; ++i)
        wpo[i] = w[(unsigned)(256 * (2 * i + 1)) * 4096u + col];
    // ---- 5) phase-2 w LAST (12 loads; ride through the exchange) ----
    float w2a[4], w2b[8];
#pragma unroll
    for (int i = 0; i < 4; ++i)
        w2a[i] = w[(unsigned)((pb + 4 * i) * 128) * 4096u + col];
#pragma unroll
    for (int i = 0; i < 8; ++i)
        w2b[i] = w[(unsigned)((pb + 4 * i) * 64) * 4096u + col];

    // ---- even twiddles (gate: rows0-7 + wpe = 11 loads) ----
    f32x2 cv1[8], sv1[8];
    cv1[0] = CV_ID; sv1[0] = SV_ID;
    tw2(512,  wpe[0], &cv1[2], &sv1[2]);
    tw2(1024, wpe[1], &cv1[4], &sv1[4]);
    tw2(1536, wpe[2], &cv1[6], &sv1[6]);

    // ---- half stages h=1,2,4 on each half ----
#pragma unroll
    for (int base = 0; base <= 8; base += 8) {
#pragma unroll
        for (int b = 0; b < 4; ++b)          // h=1, identity
            bf2(v[base + 2 * b], v[base + 2 * b + 1], CV_ID, SV_ID);
#pragma unroll
        for (int r = 0; r < 2; ++r)          // h=2, ti=4r
#pragma unroll
            for (int b = 0; b < 2; ++b) {
                int mt = base + b * 4 + r;
                bf2(v[mt], v[mt + 2], cv1[4 * r], sv1[4 * r]);
            }
#pragma unroll
        for (int r = 0; r < 4; ++r) {        // h=4, ti=2r
            int mt = base + r;
            bf2(v[mt], v[mt + 4], cv1[2 * r], sv1[2 * r]);
        }
    }

    // ---- odd twiddles then cross stage h=8 ----
    tw2(256,  wpo[0], &cv1[1], &sv1[1]);
    tw2(768,  wpo[1], &cv1[3], &sv1[3]);
    tw2(1280, wpo[2], &cv1[5], &sv1[5]);
    tw2(1792, wpo[3], &cv1[7], &sv1[7]);
#pragma unroll
    for (int r = 0; r < 8; ++r)
        bf2(v[r], v[r + 8], cv1[r], sv1[r]);

    // ---- ownership exchange (raw barriers; w2 loads still in flight) ----
    exchange(tile, v, pb, c);

    // ---- phase-2 twiddles AFTER exchange (w2 had max time to drain) ----
    f32x2 cv2a[4], sv2a[4], cv2b[8], sv2b[8];
#pragma unroll
    for (int i = 0; i < 4; ++i)
        tw2((pb + 4 * i) * 128, w2a[i], &cv2a[i], &sv2a[i]);
#pragma unroll
    for (int i = 0; i < 8; ++i)
        tw2((pb + 4 * i) * 64, w2b[i], &cv2b[i], &sv2b[i]);

    // ---- phase 2: step 32 (pairs m,m+4) then step 64 (pairs m,m+8) ----
#pragma unroll
    for (int rm = 0; rm < 4; ++rm) {
#pragma unroll
        for (int b = 0; b < 2; ++b) {
            const int mt = b * 8 + rm;
            bf2(v[mt], v[mt + 4], cv2a[rm], sv2a[rm]);
        }
    }
#pragma unroll
    for (int m = 0; m < 8; ++m)
        bf2(v[m], v[m + 8], cv2b[m], sv2b[m]);

    // ---- stores: rows r0 + pb + 4*m ----
#pragma unroll
    for (int m = 0; m < 16; ++m) {
        unsigned gi = (unsigned)(r0 + pb + 4 * m) * 4096u + col;
        if (gi < dst_lim) {
            if (HALF_OUT)
                ((unsigned*)dstv)[gi] = pack_h2(v[m]);
            else
                ((f32x2*)dstv)[gi] = v[m];
        }
    }
}

// Kernel B: stages step=128..4096 (R15 structure; packed-f32 butterflies).
// HALF_IN=1 reads the packed-fp16 intermediate.
template <int REAL_OUT, int HALF_IN>
__global__ __launch_bounds__(256) void fft_hi(const float* __restrict__ w,
                                              const void* __restrict__ srcv,
                                              f32x2* __restrict__ dstc,
                                              float* __restrict__ dstr,
                                              unsigned dst_lim) {
    __shared__ __align__(16) f32x2 tile[32 * 64];   // 16 KB, exchange only
    const int t    = threadIdx.x;
    const int c    = t & 63;
    const int pb   = t >> 6;
    const int rres = blockIdx.x >> 6;
    const unsigned col = (unsigned)(((blockIdx.x & 63) << 6) + c);

    f32x2 v[16];
    // ---- 1) data rows 0..7 ----
#pragma unroll
    for (int m = 0; m < 8; ++m) {
        unsigned gi = (unsigned)(rres + 64 * (16 * pb + m)) * 4096u + col;
        if (HALF_IN) v[m] = unpack_h2(((const unsigned*)srcv)[gi]);
        else         v[m] = ((const f32x2*)srcv)[gi];
    }
    // ---- 2) w for half stages h=1,2,4 (7 loads) ----
    float wp1, wp2[2], wp4[4];
    wp1 = w[(unsigned)(rres * 32) * 4096u + col];
#pragma unroll
    for (int r = 0; r < 2; ++r)
        wp2[r] = w[(unsigned)((rres + 64 * r) * 16) * 4096u + col];
#pragma unroll
    for (int r = 0; r < 4; ++r)
        wp4[r] = w[(unsigned)((rres + 64 * r) * 8) * 4096u + col];
    // ---- 3) data rows 8..15 ----
#pragma unroll
    for (int m = 8; m < 16; ++m) {
        unsigned gi = (unsigned)(rres + 64 * (16 * pb + m)) * 4096u + col;
        if (HALF_IN) v[m] = unpack_h2(((const unsigned*)srcv)[gi]);
        else         v[m] = ((const f32x2*)srcv)[gi];
    }
    // ---- 4) w for cross stage h=8 (8 loads) ----
    float wp8[8];
#pragma unroll
    for (int r = 0; r < 8; ++r)
        wp8[r] = w[(unsigned)((rres + 64 * r) * 4) * 4096u + col];
    // ---- 5) phase-2 w LAST (12 loads; ride through the exchange) ----
    float w2a[4], w2b[8];
#pragma unroll
    for (int i = 0; i < 4; ++i)
        w2a[i] = w[(unsigned)((rres + 64 * (pb + 4 * i)) * 2) * 4096u + col];
#pragma unroll
    for (int i = 0; i < 8; ++i)
        w2b[i] = w[(unsigned)(rres + 64 * (pb + 4 * i)) * 4096u + col];

    // ---- half-stage twiddles (gate: rows0-7 + 7 w = 15 of 43 loads) ----
    f32x2 cv1, sv1, cv2[2], sv2[2], cv4[4], sv4[4];
    tw2(rres * 32, wp1, &cv1, &sv1);
#pragma unroll
    for (int r = 0; r < 2; ++r)
        tw2((rres + 64 * r) * 16, wp2[r], &cv2[r], &sv2[r]);
#pragma unroll
    for (int r = 0; r < 4; ++r)
        tw2((rres + 64 * r) * 8, wp4[r], &cv4[r], &sv4[r]);

    // ---- half stages h=1,2,4 on each half ----
#pragma unroll
    for (int base = 0; base <= 8; base += 8) {
#pragma unroll
        for (int b = 0; b < 4; ++b)          // h=1 (global step 128)
            bf2(v[base + 2 * b], v[base + 2 * b + 1], cv1, sv1);
#pragma unroll
        for (int r = 0; r < 2; ++r)          // h=2 (step 256)
#pragma unroll
            for (int b = 0; b < 2; ++b) {
                int mt = base + b * 4 + r;
                bf2(v[mt], v[mt + 2], cv2[r], sv2[r]);
            }
#pragma unroll
        for (int r = 0; r < 4; ++r) {        // h=4 (step 512)
            int mt = base + r;
            bf2(v[mt], v[mt + 4], cv4[r], sv4[r]);
        }
    }

    // ---- cross-stage twiddles then h=8 (global step 1024) ----
#pragma unroll
    for (int r = 0; r < 8; ++r) {
        f32x2 cvx, svx;
        tw2((rres + 64 * r) * 4, wp8[r], &cvx, &svx);
        bf2(v[r], v[r + 8], cvx, svx);
    }

    // ---- ownership exchange (raw barriers; w2 loads still in flight) ----
    exchange(tile, v, pb, c);

    // ---- phase-2 twiddles AFTER exchange ----
    f32x2 cv2a[4], sv2a[4], cv2b[8], sv2b[8];
#pragma unroll
    for (int i = 0; i < 4; ++i)
        tw2((rres + 64 * (pb + 4 * i)) * 2, w2a[i], &cv2a[i], &sv2a[i]);
#pragma unroll
    for (int i = 0; i < 8; ++i)
        tw2(rres + 64 * (pb + 4 * i), w2b[i], &cv2b[i], &sv2b[i]);

    // ---- phase 2: global steps 2048 (m,m+4) and 4096 (m,m+8) ----
#pragma unroll
    for (int rm = 0; rm < 4; ++rm) {
#pragma unroll
        for (int b = 0; b < 2; ++b) {
            const int mt = b * 8 + rm;
            bf2(v[mt], v[mt + 4], cv2a[rm], sv2a[rm]);
        }
    }
#pragma unroll
    for (int m = 0; m < 8; ++m)
        bf2(v[m], v[m + 8], cv2b[m], sv2b[m]);

    // ---- stores: rows rres + 64*(pb+4*m), row-major output ----
    if (REAL_OUT) {
#pragma unroll
        for (int m = 0; m < 16; ++m) {
            unsigned gi = (unsigned)(rres + 64 * (pb + 4 * m)) * 4096u + col;
            if (gi < dst_lim) __builtin_nontemporal_store(v[m].x, &dstr[gi]);
        }
    } else {
#pragma unroll
        for (int m = 0; m < 16; ++m) {
            unsigned gi = (unsigned)(rres + 64 * (pb + 4 * m)) * 4096u + col;
            if (gi < dst_lim) dstc[gi] = v[m];
        }
    }
}

extern "C" void kernel_launch(void* const* d_in, const int* in_sizes, int n_in,
                              void* d_out, int out_size, void* d_ws, size_t ws_size,
                              hipStream_t stream) {
    const float* x = (const float*)d_in[0];
    const float* w = (const float*)d_in[1];
    const long long NN = 4096LL * 4096LL;

    if ((long long)out_size >= 2 * NN) {
        // d_out = interleaved complex (2*N*N floats): fp32 in-place (output
        // format fixed; no fp16 shortcut possible here).
        unsigned lim2 = (unsigned)(out_size / 2);          // float2 units
        fft_lo<0><<<4096, 256, 0, stream>>>(x, w, d_out, lim2);
        fft_hi<0, 0><<<4096, 256, 0, stream>>>(w, d_out, (f32x2*)d_out,
                                               nullptr, lim2);
    } else {
        // Confirmed world: d_out = N*N floats (real part). Intermediate in
        // d_ws as PACKED FP16 half2 (4 B/elem — R15: FETCH 90->54 MB,
        // fft_hi 50->43 us; absmax unchanged).
        unsigned ws_lim_h2 = (unsigned)(ws_size / 4);      // half2 element units
        unsigned out_lim   = (unsigned)out_size;           // float units
        fft_lo<1><<<4096, 256, 0, stream>>>(x, w, d_ws, ws_lim_h2);
        fft_hi<1, 1><<<4096, 256, 0, stream>>>(w, d_ws, nullptr,
                                               (float*)d_out, out_lim);
    }
}

// Round 17
// 188.745 us; speedup vs baseline: 2.8472x; 2.8472x over previous
//
#include <hip/hip_runtime.h>

#define INV_N (1.0f / 4096.0f)

typedef __fp16 half2_t __attribute__((ext_vector_type(2)));

__device__ __forceinline__ unsigned pack_h2(float a, float b) {
    half2_t h = __builtin_amdgcn_cvt_pkrtz(a, b);   // v_cvt_pkrtz_f16_f32
    return __builtin_bit_cast(unsigned, h);
}
__device__ __forceinline__ float2 unpack_h2(unsigned u) {
    half2_t h = __builtin_bit_cast(half2_t, u);
    return make_float2((float)h.x, (float)h.y);
}

// Scalar butterfly. R16 ERRATum: the f32x2 packed-math rewrite ballooned
// VGPR 44->244 (cv/sv pairs double twiddle storage; ext-vector values force
// even-aligned pairs) and spilled (WRITE_SIZE +40 MB) -> 5x slowdown.
// The scalar form's register economy IS the win; keep it.
__device__ __forceinline__ void bf(float& ar, float& ai, float& br, float& bi,
                                   float s, float cs) {
    float tr = cs * br - s * bi;
    float ti = cs * bi + s * br;
    br = ar - tr; bi = ai - ti;
    ar = ar + tr; ai = ai + ti;
}

// Twiddle: angle = -2pi*(k/4096)*wk radians => rev = -(k/4096)*wk revolutions.
__device__ __forceinline__ void tw(int k, float wk, float* s, float* cs) {
    float rev = (float)k * (-INV_N) * wk;
    rev = __builtin_amdgcn_fractf(rev);          // [0,1), handles negatives
    *s  = __builtin_amdgcn_sinf(rev);            // sin(2*pi*rev)
    *cs = __builtin_amdgcn_cosf(rev);            // cos(2*pi*rev)
}

// Raw barrier with LDS-only drain. __syncthreads() would emit
// "s_waitcnt vmcnt(0) lgkmcnt(0)" and drain the global-load queue at every
// exchange barrier; lgkmcnt(0)-only lets in-flight global loads ride through
// (R10: the only overlap lever that measurably helped).
#define BAR() do { asm volatile("s_waitcnt lgkmcnt(0)" ::: "memory"); \
                   __builtin_amdgcn_s_barrier(); } while (0)

// Two-round 16 KB ownership exchange: consecutive-16 rows -> stride-4 rows.
// Parity predicate (pb + (m>>2) + (m&3)) & 1: what a thread flushes in a
// round is exactly what it refills in that round (no extra live VGPRs).
__device__ __forceinline__ void exchange(float2* tile, float (&ar)[16],
                                         float (&ai)[16], int pb, int c) {
#pragma unroll
    for (int par = 0; par < 2; ++par) {
#pragma unroll
        for (int m = 0; m < 16; ++m) {
            if (((pb + (m >> 2) + (m & 3)) & 1) == par) {
                int srow = (pb << 3) + (((m >> 2) << 1) | ((m & 3) >> 1));
                tile[srow * 64 + c] = make_float2(ar[m], ai[m]);
            }
        }
        BAR();
#pragma unroll
        for (int m = 0; m < 16; ++m) {
            if (((pb + (m >> 2) + (m & 3)) & 1) == par) {
                int srow = ((m >> 2) << 3) + ((m & 3) << 1) + (pb >> 1);
                float2 v = tile[srow * 64 + c];
                ar[m] = v.x; ai[m] = v.y;
            }
        }
        if (par == 0) BAR();
    }
}

// Kernel A: stages step=2..64 (R15 verbatim — best: 188.8 us total).
// HALF_OUT=1 stores the intermediate as packed fp16 half2 (4 B/element):
// R15 confirmed mem phases run at the BW ceiling, so bytes set mem time
// (FETCH 90->54 MB, fft_hi 50->43 us; absmax unchanged).
template <int HALF_OUT>
__global__ __launch_bounds__(256) void fft_lo(const float* __restrict__ x,
                                              const float* __restrict__ w,
                                              void* __restrict__ dstv,
                                              unsigned dst_lim) {   // element units
    __shared__ __align__(16) float2 tile[32 * 64];   // 16 KB, exchange only
    const int t   = threadIdx.x;
    const int c   = t & 63;
    const int pb  = t >> 6;
    const int c0  = (blockIdx.x & 63) << 6;
    const int r0  = (blockIdx.x >> 6) << 6;
    const int src_r0 = r0 ^ 2048;      // initial permutation: new[i] = old[i^2048]
    const unsigned col = (unsigned)(c0 + c);

    float ar[16], ai[16];
    // ---- 1) data rows 0..7 ----
#pragma unroll
    for (int m = 0; m < 8; ++m) {
        unsigned gi = (unsigned)(src_r0 + 16 * pb + m) * 4096u + col;
        ar[m] = __builtin_nontemporal_load(&x[gi]);
        ai[m] = 0.f;
    }
    // ---- 2) w for half-stage twiddles s1[2],s1[4],s1[6] ----
    float wpe[3];
#pragma unroll
    for (int i = 0; i < 3; ++i)
        wpe[i] = w[(unsigned)(512 * (i + 1)) * 4096u + col];
    // ---- 3) data rows 8..15 ----
#pragma unroll
    for (int m = 8; m < 16; ++m) {
        unsigned gi = (unsigned)(src_r0 + 16 * pb + m) * 4096u + col;
        ar[m] = __builtin_nontemporal_load(&x[gi]);
        ai[m] = 0.f;
    }
    // ---- 4) w for cross-stage twiddles s1[1,3,5,7] ----
    float wpo[4];
#pragma unroll
    for (int i = 0; i < 4; ++i)
        wpo[i] = w[(unsigned)(256 * (2 * i + 1)) * 4096u + col];
    // ---- 5) phase-2 w LAST (12 loads; ride through the exchange) ----
    float w2a[4], w2b[8];
#pragma unroll
    for (int i = 0; i < 4; ++i)
        w2a[i] = w[(unsigned)((pb + 4 * i) * 128) * 4096u + col];
#pragma unroll
    for (int i = 0; i < 8; ++i)
        w2b[i] = w[(unsigned)((pb + 4 * i) * 64) * 4096u + col];

    // ---- even twiddles (gate: rows0-7 + wpe = 11 loads) ----
    float s1[8], c1[8];
    s1[0] = 0.f; c1[0] = 1.f;
    tw(512,  wpe[0], &s1[2], &c1[2]);
    tw(1024, wpe[1], &s1[4], &c1[4]);
    tw(1536, wpe[2], &s1[6], &c1[6]);

    // ---- half stages h=1,2,4 on each half ----
#pragma unroll
    for (int base = 0; base <= 8; base += 8) {
#pragma unroll
        for (int b = 0; b < 4; ++b)          // h=1, identity
            bf(ar[base + 2 * b], ai[base + 2 * b],
               ar[base + 2 * b + 1], ai[base + 2 * b + 1], 0.f, 1.f);
#pragma unroll
        for (int r = 0; r < 2; ++r)          // h=2, ti=4r
#pragma unroll
            for (int b = 0; b < 2; ++b) {
                int mt = base + b * 4 + r;
                bf(ar[mt], ai[mt], ar[mt + 2], ai[mt + 2], s1[4 * r], c1[4 * r]);
            }
#pragma unroll
        for (int r = 0; r < 4; ++r) {        // h=4, ti=2r
            int mt = base + r;
            bf(ar[mt], ai[mt], ar[mt + 4], ai[mt + 4], s1[2 * r], c1[2 * r]);
        }
    }

    // ---- odd twiddles then cross stage h=8 ----
    tw(256,  wpo[0], &s1[1], &c1[1]);
    tw(768,  wpo[1], &s1[3], &c1[3]);
    tw(1280, wpo[2], &s1[5], &c1[5]);
    tw(1792, wpo[3], &s1[7], &c1[7]);
#pragma unroll
    for (int r = 0; r < 8; ++r)
        bf(ar[r], ai[r], ar[r + 8], ai[r + 8], s1[r], c1[r]);

    // ---- ownership exchange (raw barriers; w2 loads still in flight) ----
    exchange(tile, ar, ai, pb, c);

    // ---- phase-2 twiddles AFTER exchange (w2 had max time to drain) ----
    float s2a[4], c2a[4], s2b[8], c2b[8];
#pragma unroll
    for (int i = 0; i < 4; ++i)
        tw((pb + 4 * i) * 128, w2a[i], &s2a[i], &c2a[i]);
#pragma unroll
    for (int i = 0; i < 8; ++i)
        tw((pb + 4 * i) * 64, w2b[i], &s2b[i], &c2b[i]);

    // ---- phase 2: step 32 (pairs m,m+4) then step 64 (pairs m,m+8) ----
#pragma unroll
    for (int rm = 0; rm < 4; ++rm) {
#pragma unroll
        for (int b = 0; b < 2; ++b) {
            const int mt = b * 8 + rm;
            bf(ar[mt], ai[mt], ar[mt + 4], ai[mt + 4], s2a[rm], c2a[rm]);
        }
    }
#pragma unroll
    for (int m = 0; m < 8; ++m)
        bf(ar[m], ai[m], ar[m + 8], ai[m + 8], s2b[m], c2b[m]);

    // ---- stores: rows r0 + pb + 4*m ----
#pragma unroll
    for (int m = 0; m < 16; ++m) {
        unsigned gi = (unsigned)(r0 + pb + 4 * m) * 4096u + col;
        if (gi < dst_lim) {
            if (HALF_OUT)
                ((unsigned*)dstv)[gi] = pack_h2(ar[m], ai[m]);
            else
                ((float2*)dstv)[gi] = make_float2(ar[m], ai[m]);
        }
    }
}

// Kernel B: stages step=128..4096 (R15 verbatim). HALF_IN=1 reads the
// packed-fp16 intermediate (halves FETCH traffic of the dominant input).
template <int REAL_OUT, int HALF_IN>
__global__ __launch_bounds__(256) void fft_hi(const float* __restrict__ w,
                                              const void* __restrict__ srcv,
                                              float2* __restrict__ dstc,
                                              float* __restrict__ dstr,
                                              unsigned dst_lim) {
    __shared__ __align__(16) float2 tile[32 * 64];   // 16 KB, exchange only
    const int t    = threadIdx.x;
    const int c    = t & 63;
    const int pb   = t >> 6;
    const int rres = blockIdx.x >> 6;
    const unsigned col = (unsigned)(((blockIdx.x & 63) << 6) + c);

    float ar[16], ai[16];
    // ---- 1) data rows 0..7 ----
#pragma unroll
    for (int m = 0; m < 8; ++m) {
        unsigned gi = (unsigned)(rres + 64 * (16 * pb + m)) * 4096u + col;
        float2 v;
        if (HALF_IN) v = unpack_h2(((const unsigned*)srcv)[gi]);
        else         v = ((const float2*)srcv)[gi];
        ar[m] = v.x; ai[m] = v.y;
    }
    // ---- 2) w for half stages h=1,2,4 (7 loads) ----
    float wp1, wp2[2], wp4[4];
    wp1 = w[(unsigned)(rres * 32) * 4096u + col];
#pragma unroll
    for (int r = 0; r < 2; ++r)
        wp2[r] = w[(unsigned)((rres + 64 * r) * 16) * 4096u + col];
#pragma unroll
    for (int r = 0; r < 4; ++r)
        wp4[r] = w[(unsigned)((rres + 64 * r) * 8) * 4096u + col];
    // ---- 3) data rows 8..15 ----
#pragma unroll
    for (int m = 8; m < 16; ++m) {
        unsigned gi = (unsigned)(rres + 64 * (16 * pb + m)) * 4096u + col;
        float2 v;
        if (HALF_IN) v = unpack_h2(((const unsigned*)srcv)[gi]);
        else         v = ((const float2*)srcv)[gi];
        ar[m] = v.x; ai[m] = v.y;
    }
    // ---- 4) w for cross stage h=8 (8 loads) ----
    float wp8[8];
#pragma unroll
    for (int r = 0; r < 8; ++r)
        wp8[r] = w[(unsigned)((rres + 64 * r) * 4) * 4096u + col];
    // ---- 5) phase-2 w LAST (12 loads; ride through the exchange) ----
    float w2a[4], w2b[8];
#pragma unroll
    for (int i = 0; i < 4; ++i)
        w2a[i] = w[(unsigned)((rres + 64 * (pb + 4 * i)) * 2) * 4096u + col];
#pragma unroll
    for (int i = 0; i < 8; ++i)
        w2b[i] = w[(unsigned)(rres + 64 * (pb + 4 * i)) * 4096u + col];

    // ---- half-stage twiddles (gate: rows0-7 + 7 w = 15 of 43 loads) ----
    float st1, ct1, st2[2], ct2[2], st4[4], ct4[4];
    tw(rres * 32, wp1, &st1, &ct1);
#pragma unroll
    for (int r = 0; r < 2; ++r)
        tw((rres + 64 * r) * 16, wp2[r], &st2[r], &ct2[r]);
#pragma unroll
    for (int r = 0; r < 4; ++r)
        tw((rres + 64 * r) * 8, wp4[r], &st4[r], &ct4[r]);

    // ---- half stages h=1,2,4 on each half ----
#pragma unroll
    for (int base = 0; base <= 8; base += 8) {
#pragma unroll
        for (int b = 0; b < 4; ++b)          // h=1 (global step 128)
            bf(ar[base + 2 * b], ai[base + 2 * b],
               ar[base + 2 * b + 1], ai[base + 2 * b + 1], st1, ct1);
#pragma unroll
        for (int r = 0; r < 2; ++r)          // h=2 (step 256)
#pragma unroll
            for (int b = 0; b < 2; ++b) {
                int mt = base + b * 4 + r;
                bf(ar[mt], ai[mt], ar[mt + 2], ai[mt + 2], st2[r], ct2[r]);
            }
#pragma unroll
        for (int r = 0; r < 4; ++r) {        // h=4 (step 512)
            int mt = base + r;
            bf(ar[mt], ai[mt], ar[mt + 4], ai[mt + 4], st4[r], ct4[r]);
        }
    }

    // ---- cross-stage twiddles then h=8 (global step 1024) ----
#pragma unroll
    for (int r = 0; r < 8; ++r) {
        float s, cs;
        tw((rres + 64 * r) * 4, wp8[r], &s, &cs);
        bf(ar[r], ai[r], ar[r + 8], ai[r + 8], s, cs);
    }

    // ---- ownership exchange (raw barriers; w2 loads still in flight) ----
    exchange(tile, ar, ai, pb, c);

    // ---- phase-2 twiddles AFTER exchange ----
    float s2a[4], c2a[4], s2b[8], c2b[8];
#pragma unroll
    for (int i = 0; i < 4; ++i)
        tw((rres + 64 * (pb + 4 * i)) * 2, w2a[i], &s2a[i], &c2a[i]);
#pragma unroll
    for (int i = 0; i < 8; ++i)
        tw(rres + 64 * (pb + 4 * i), w2b[i], &s2b[i], &c2b[i]);

    // ---- phase 2: global steps 2048 (m,m+4) and 4096 (m,m+8) ----
#pragma unroll
    for (int rm = 0; rm < 4; ++rm) {
#pragma unroll
        for (int b = 0; b < 2; ++b) {
            const int mt = b * 8 + rm;
            bf(ar[mt], ai[mt], ar[mt + 4], ai[mt + 4], s2a[rm], c2a[rm]);
        }
    }
#pragma unroll
    for (int m = 0; m < 8; ++m)
        bf(ar[m], ai[m], ar[m + 8], ai[m + 8], s2b[m], c2b[m]);

    // ---- stores: rows rres + 64*(pb+4*m), row-major output ----
    if (REAL_OUT) {
#pragma unroll
        for (int m = 0; m < 16; ++m) {
            unsigned gi = (unsigned)(rres + 64 * (pb + 4 * m)) * 4096u + col;
            if (gi < dst_lim) __builtin_nontemporal_store(ar[m], &dstr[gi]);
        }
    } else {
#pragma unroll
        for (int m = 0; m < 16; ++m) {
            unsigned gi = (unsigned)(rres + 64 * (pb + 4 * m)) * 4096u + col;
            if (gi < dst_lim) dstc[gi] = make_float2(ar[m], ai[m]);
        }
    }
}

extern "C" void kernel_launch(void* const* d_in, const int* in_sizes, int n_in,
                              void* d_out, int out_size, void* d_ws, size_t ws_size,
                              hipStream_t stream) {
    const float* x = (const float*)d_in[0];
    const float* w = (const float*)d_in[1];
    const long long NN = 4096LL * 4096LL;

    if ((long long)out_size >= 2 * NN) {
        // d_out = interleaved complex (2*N*N floats): fp32 in-place (output
        // format fixed; no fp16 shortcut possible here).
        unsigned lim2 = (unsigned)(out_size / 2);          // float2 units
        fft_lo<0><<<4096, 256, 0, stream>>>(x, w, d_out, lim2);
        fft_hi<0, 0><<<4096, 256, 0, stream>>>(w, d_out, (float2*)d_out,
                                               nullptr, lim2);
    } else {
        // Confirmed world: d_out = N*N floats (real part). Intermediate in
        // d_ws as PACKED FP16 half2 (4 B/elem — R15: FETCH 90->54 MB,
        // fft_hi 50->43 us; absmax unchanged).
        unsigned ws_lim_h2 = (unsigned)(ws_size / 4);      // half2 element units
        unsigned out_lim   = (unsigned)out_size;           // float units
        fft_lo<1><<<4096, 256, 0, stream>>>(x, w, d_ws, ws_lim_h2);
        fft_hi<1, 1><<<4096, 256, 0, stream>>>(w, d_ws, nullptr,
                                               (float*)d_out, out_lim);
    }
}